// Round 4
// baseline (1973.387 us; speedup 1.0000x reference)
//
#include <hip/hip_runtime.h>
#include <hip/hip_fp16.h>
#include <math.h>

#define NN 50000
#define IND 128
#define NH 4
#define NE 800000
#define NT 3
#define NSLOPE 0.2f

#define TILE 64                    // dsts per bucket
#define NBPT 782                   // ceil(NN/TILE)
#define NBTOT (NT * NBPT)          // 2346
#define BCAP 1280                  // slots per bucket (Poisson λ=1024, +8σ)

// ---------------- GEMM + fused e_src/e_dst, h stored fp16 ----------------
// One wave = 8 rows x 128 cols; lane owns dims (2l, 2l+1).
// ws[k*64+l] = {W[k][2l], W[k][2l+1]} -> conflict-free ds_read_b64 (verified 0 conflicts r3).
__global__ __launch_bounds__(256) void gemm_esrc_kernel(
    const float* __restrict__ x, const float* __restrict__ Wt,
    const float* __restrict__ asrc, const float* __restrict__ adst,
    __half* __restrict__ h16, float* __restrict__ es, float* __restrict__ ed)
{
    __shared__ float2 ws[IND * 64];
    const int tid = threadIdx.x;
    for (int idx = tid; idx < IND * 64; idx += 256) {
        int k = idx >> 6, l = idx & 63;
        ws[idx] = *reinterpret_cast<const float2*>(Wt + k * IND + 2 * l);
    }
    __syncthreads();

    const int wv   = __builtin_amdgcn_readfirstlane(tid >> 6);
    const int lane = tid & 63;
    const int n0   = blockIdx.x * 32 + wv * 8;
    if (n0 >= NN) return;

    const float2 aa = *reinterpret_cast<const float2*>(asrc + 2 * lane);
    const float2 bb = *reinterpret_cast<const float2*>(adst + 2 * lane);

    float accA[8] = {0,0,0,0,0,0,0,0};   // dim 2*lane
    float accB[8] = {0,0,0,0,0,0,0,0};   // dim 2*lane+1

    const float4* xr0 = reinterpret_cast<const float4*>(x + (size_t)n0 * IND);

    #pragma unroll 4
    for (int kc = 0; kc < 32; kc++) {
        float2 w0 = ws[(kc * 4 + 0) * 64 + lane];
        float2 w1 = ws[(kc * 4 + 1) * 64 + lane];
        float2 w2 = ws[(kc * 4 + 2) * 64 + lane];
        float2 w3 = ws[(kc * 4 + 3) * 64 + lane];
        #pragma unroll
        for (int r = 0; r < 8; r++) {
            float4 xv = xr0[r * 32 + kc];       // wave-uniform -> scalar loads
            accA[r] = fmaf(xv.x, w0.x, accA[r]);
            accB[r] = fmaf(xv.x, w0.y, accB[r]);
            accA[r] = fmaf(xv.y, w1.x, accA[r]);
            accB[r] = fmaf(xv.y, w1.y, accB[r]);
            accA[r] = fmaf(xv.z, w2.x, accA[r]);
            accB[r] = fmaf(xv.z, w2.y, accB[r]);
            accA[r] = fmaf(xv.w, w3.x, accA[r]);
            accB[r] = fmaf(xv.w, w3.y, accB[r]);
        }
    }

    #pragma unroll
    for (int r = 0; r < 8; r++) {
        const int n = n0 + r;
        __half2* hrow = reinterpret_cast<__half2*>(h16 + (size_t)n * IND);
        hrow[lane] = __float22half2_rn(make_float2(accA[r], accB[r]));
        float vs = accA[r] * aa.x + accB[r] * aa.y;
        float vd = accA[r] * bb.x + accB[r] * bb.y;
        #pragma unroll
        for (int m = 1; m <= 8; m <<= 1) {      // reduce 16-lane head groups
            vs += __shfl_xor(vs, m, 64);
            vd += __shfl_xor(vd, m, 64);
        }
        if ((lane & 15) == 0) {
            es[n * NH + (lane >> 4)] = vs;
            ed[n * NH + (lane >> 4)] = vd;
        }
    }
}

// ---------------- bucket init + scatter ----------------
__global__ __launch_bounds__(256) void init_gcursor_kernel(int* __restrict__ gcursor)
{
    int i = blockIdx.x * 256 + threadIdx.x;
    if (i < NBTOT) gcursor[i] = i * BCAP;
}

// 16384 edges per WG: LDS hist -> global reservation -> packed coalesced-run writes
__global__ __launch_bounds__(512) void bucket_scatter_kernel(
    const int* __restrict__ edges, int* __restrict__ gcursor, unsigned* __restrict__ bucketed)
{
    __shared__ int cnt[NBTOT];
    __shared__ int base[NBTOT];
    const int tid = threadIdx.x;
    for (int i = tid; i < NBTOT; i += 512) cnt[i] = 0;
    __syncthreads();
    const long long gtot = (long long)NT * NE;
    const long long g0 = (long long)blockIdx.x * 16384;
    long long g1 = g0 + 16384; if (g1 > gtot) g1 = gtot;
    // pass A: histogram (dst only)
    for (long long g = g0 + tid; g < g1; g += 512) {
        int t = (g >= 2LL * NE) ? 2 : (g >= NE ? 1 : 0);
        int e = (int)(g - (long long)t * NE);
        int d = edges[(size_t)t * 2 * NE + NE + e];
        atomicAdd(&cnt[t * NBPT + (d >> 6)], 1);
    }
    __syncthreads();
    // pass B: reserve per-bucket runs
    for (int i = tid; i < NBTOT; i += 512) {
        int c = cnt[i];
        base[i] = c ? atomicAdd(&gcursor[i], c) : 0;
        cnt[i] = 0;
    }
    __syncthreads();
    // pass C: scatter packed {src | dlow<<16}
    for (long long g = g0 + tid; g < g1; g += 512) {
        int t = (g >= 2LL * NE) ? 2 : (g >= NE ? 1 : 0);
        int e = (int)(g - (long long)t * NE);
        const int* eb = edges + (size_t)t * 2 * NE;
        int s = eb[e], d = eb[NE + e];
        int bg = t * NBPT + (d >> 6);
        int pos = base[bg] + atomicAdd(&cnt[bg], 1);
        bucketed[pos] = (unsigned)s | ((unsigned)(d & 63) << 16);
    }
}

// ---------------- fused score+softmax+aggregate+ELU over LDS dst-tiles ----------------
__global__ __launch_bounds__(512) void gat_lds_kernel(
    const unsigned* __restrict__ bucketed, const int* __restrict__ gcursor,
    const __half* __restrict__ h16,
    const float* __restrict__ es, const float* __restrict__ ed,
    float* __restrict__ out)
{
    __shared__ float agg[TILE * IND];   // 32 KB
    __shared__ float den[TILE * NH];    // 1 KB
    __shared__ float edS[TILE * NH];    // 1 KB
    const int bg = blockIdx.x;
    const int t  = bg / NBPT;
    const int b  = bg - t * NBPT;
    const int node0 = b * TILE;
    const int tid = threadIdx.x;

    for (int i = tid; i < TILE * IND; i += 512) agg[i] = 0.f;
    for (int i = tid; i < TILE * NH; i += 512) {
        den[i] = 0.f;
        int node = node0 + (i >> 2);
        edS[i] = (node < NN) ? ed[((size_t)t * NN + node) * NH + (i & 3)] : 0.f;
    }
    __syncthreads();

    const int lane = tid & 63;
    const int wv   = tid >> 6;           // 8 waves
    const int hd   = lane >> 4;          // head of dims (2l, 2l+1)
    const int beg  = bg * BCAP;
    const int end  = gcursor[bg];
    const float*  es_t  = es + (size_t)t * NN * NH;
    const __half* h16_t = h16 + (size_t)t * NN * IND;

    for (int e = beg + wv; e < end; e += 8) {
        int eu = __builtin_amdgcn_readfirstlane(e);
        unsigned pk = bucketed[eu];
        int src  = (int)(pk & 0xFFFFu);
        int dlow = (int)((pk >> 16) & 63u);
        __half2 hv = *reinterpret_cast<const __half2*>(h16_t + (size_t)src * IND + 2 * lane);
        float s = es_t[src * NH + hd] + edS[dlow * NH + hd];
        s = s > 0.f ? s : NSLOPE * s;
        float w = __expf(s);
        float2 hf = __half22float2(hv);
        unsafeAtomicAdd(&agg[dlow * IND + 2 * lane],     hf.x * w);
        unsafeAtomicAdd(&agg[dlow * IND + 2 * lane + 1], hf.y * w);
        if ((lane & 15) == 0) unsafeAtomicAdd(&den[dlow * NH + hd], w);
    }
    __syncthreads();

    float* outa = out + (size_t)t * NN * IND;
    float* outb = out + (size_t)(NT + t) * NN * IND;
    for (int i = tid; i < TILE * IND; i += 512) {
        int dlow = i >> 7;
        int node = node0 + dlow;
        if (node >= NN) continue;
        float v = agg[i] / (den[dlow * NH + ((i & 127) >> 5)] + 1e-9f);
        float r = v > 0.f ? v : expm1f(v);
        size_t o = (size_t)node * IND + (i & 127);
        outa[o] = r;
        outb[o] = r;
    }
}

extern "C" void kernel_launch(void* const* d_in, const int* in_sizes, int n_in,
                              void* d_out, int out_size, void* d_ws, size_t ws_size,
                              hipStream_t stream)
{
    const float* x     = (const float*)d_in[0];
    const int*   edges = (const int*)d_in[1];
    const float* W     = (const float*)d_in[2];
    const float* asrc  = (const float*)d_in[3];
    const float* adst  = (const float*)d_in[4];
    float* out = (float*)d_out;

    char* p = (char*)d_ws;
    __half*   h16      = (__half*)p;   p += (size_t)NT * NN * IND * 2;   // 38.4 MB
    float*    es       = (float*)p;    p += (size_t)NT * NN * NH * 4;    // 2.4 MB
    float*    ed       = (float*)p;    p += (size_t)NT * NN * NH * 4;    // 2.4 MB
    int*      gcursor  = (int*)p;      p += (size_t)NBTOT * 4;
    unsigned* bucketed = (unsigned*)p; p += ((size_t)NBTOT * BCAP + 1024) * 4;  // 12 MB + slack

    init_gcursor_kernel<<<(NBTOT + 255) / 256, 256, 0, stream>>>(gcursor);
    bucket_scatter_kernel<<<(NT * NE + 16383) / 16384, 512, 0, stream>>>(edges, gcursor, bucketed);

    for (int t = 0; t < NT; t++) {
        gemm_esrc_kernel<<<(NN + 31) / 32, 256, 0, stream>>>(
            x, W + (size_t)t * IND * IND,
            asrc + (size_t)t * NH * 32, adst + (size_t)t * NH * 32,
            h16 + (size_t)t * NN * IND,
            es + (size_t)t * NN * NH, ed + (size_t)t * NN * NH);
    }

    gat_lds_kernel<<<NBTOT, 512, 0, stream>>>(bucketed, gcursor, h16, es, ed, out);
}

// Round 5
// 419.515 us; speedup vs baseline: 4.7040x; 4.7040x over previous
//
#include <hip/hip_runtime.h>
#include <hip/hip_fp16.h>
#include <math.h>

#define NN 50000
#define IND 128
#define NH 4
#define NE 800000
#define NT 3
#define NSLOPE 0.2f

#define TILE 64                    // dsts per bucket
#define NBPT 782                   // ceil(NN/TILE)
#define NBTOT (NT * NBPT)          // 2346
#define BCAP 1280                  // slots per bucket (Poisson λ=1024, +8σ)

// ---------------- GEMM + fused e_src/e_dst, h stored fp16 ----------------
// One wave = 8 rows x 128 cols; lane owns dims (2l, 2l+1).
__global__ __launch_bounds__(256) void gemm_esrc_kernel(
    const float* __restrict__ x, const float* __restrict__ Wt,
    const float* __restrict__ asrc, const float* __restrict__ adst,
    __half* __restrict__ h16, float* __restrict__ es, float* __restrict__ ed)
{
    __shared__ float2 ws[IND * 64];   // ws[k*64+l] = {W[k][2l], W[k][2l+1]}
    const int tid = threadIdx.x;
    for (int idx = tid; idx < IND * 64; idx += 256) {
        int k = idx >> 6, l = idx & 63;
        ws[idx] = *reinterpret_cast<const float2*>(Wt + k * IND + 2 * l);
    }
    __syncthreads();

    const int wv   = __builtin_amdgcn_readfirstlane(tid >> 6);
    const int lane = tid & 63;
    const int n0   = blockIdx.x * 32 + wv * 8;
    if (n0 >= NN) return;

    const float2 aa = *reinterpret_cast<const float2*>(asrc + 2 * lane);
    const float2 bb = *reinterpret_cast<const float2*>(adst + 2 * lane);

    float accA[8] = {0,0,0,0,0,0,0,0};   // dim 2*lane
    float accB[8] = {0,0,0,0,0,0,0,0};   // dim 2*lane+1

    const float4* xr0 = reinterpret_cast<const float4*>(x + (size_t)n0 * IND);

    #pragma unroll 4
    for (int kc = 0; kc < 32; kc++) {
        float2 w0 = ws[(kc * 4 + 0) * 64 + lane];
        float2 w1 = ws[(kc * 4 + 1) * 64 + lane];
        float2 w2 = ws[(kc * 4 + 2) * 64 + lane];
        float2 w3 = ws[(kc * 4 + 3) * 64 + lane];
        #pragma unroll
        for (int r = 0; r < 8; r++) {
            float4 xv = xr0[r * 32 + kc];       // wave-uniform -> scalar loads
            accA[r] = fmaf(xv.x, w0.x, accA[r]);
            accB[r] = fmaf(xv.x, w0.y, accB[r]);
            accA[r] = fmaf(xv.y, w1.x, accA[r]);
            accB[r] = fmaf(xv.y, w1.y, accB[r]);
            accA[r] = fmaf(xv.z, w2.x, accA[r]);
            accB[r] = fmaf(xv.z, w2.y, accB[r]);
            accA[r] = fmaf(xv.w, w3.x, accA[r]);
            accB[r] = fmaf(xv.w, w3.y, accB[r]);
        }
    }

    #pragma unroll
    for (int r = 0; r < 8; r++) {
        const int n = n0 + r;
        __half2* hrow = reinterpret_cast<__half2*>(h16 + (size_t)n * IND);
        hrow[lane] = __float22half2_rn(make_float2(accA[r], accB[r]));
        float vs = accA[r] * aa.x + accB[r] * aa.y;
        float vd = accA[r] * bb.x + accB[r] * bb.y;
        #pragma unroll
        for (int m = 1; m <= 8; m <<= 1) {      // reduce 16-lane head groups
            vs += __shfl_xor(vs, m, 64);
            vd += __shfl_xor(vd, m, 64);
        }
        if ((lane & 15) == 0) {
            es[n * NH + (lane >> 4)] = vs;
            ed[n * NH + (lane >> 4)] = vd;
        }
    }
}

// ---------------- bucket init + scatter ----------------
__global__ __launch_bounds__(256) void init_gcursor_kernel(int* __restrict__ gcursor)
{
    int i = blockIdx.x * 256 + threadIdx.x;
    if (i < NBTOT) gcursor[i] = i * BCAP;
}

// 16384 edges per WG: LDS hist -> global reservation -> packed coalesced-run writes
__global__ __launch_bounds__(512) void bucket_scatter_kernel(
    const int* __restrict__ edges, int* __restrict__ gcursor, unsigned* __restrict__ bucketed)
{
    __shared__ int cnt[NBTOT];
    __shared__ int base[NBTOT];
    const int tid = threadIdx.x;
    for (int i = tid; i < NBTOT; i += 512) cnt[i] = 0;
    __syncthreads();
    const long long gtot = (long long)NT * NE;
    const long long g0 = (long long)blockIdx.x * 16384;
    long long g1 = g0 + 16384; if (g1 > gtot) g1 = gtot;
    for (long long g = g0 + tid; g < g1; g += 512) {
        int t = (g >= 2LL * NE) ? 2 : (g >= NE ? 1 : 0);
        int e = (int)(g - (long long)t * NE);
        int d = edges[(size_t)t * 2 * NE + NE + e];
        atomicAdd(&cnt[t * NBPT + (d >> 6)], 1);
    }
    __syncthreads();
    for (int i = tid; i < NBTOT; i += 512) {
        int c = cnt[i];
        base[i] = c ? atomicAdd(&gcursor[i], c) : 0;
        cnt[i] = 0;
    }
    __syncthreads();
    for (long long g = g0 + tid; g < g1; g += 512) {
        int t = (g >= 2LL * NE) ? 2 : (g >= NE ? 1 : 0);
        int e = (int)(g - (long long)t * NE);
        const int* eb = edges + (size_t)t * 2 * NE;
        int s = eb[e], d = eb[NE + e];
        int bg = t * NBPT + (d >> 6);
        int pos = base[bg] + atomicAdd(&cnt[bg], 1);
        bucketed[pos] = (unsigned)s | ((unsigned)(d & 63) << 16);
    }
}

// ---------------- per-bucket in-LDS counting sort -> exact per-dst CSR (in place) ----------------
__global__ __launch_bounds__(256) void bucket_sort_kernel(
    unsigned* __restrict__ bucketed, const int* __restrict__ gcursor,
    int* __restrict__ begA, int* __restrict__ endA)
{
    __shared__ unsigned pk[BCAP];
    __shared__ unsigned srt[BCAP];
    __shared__ int hist[TILE];
    __shared__ int scn[TILE];
    __shared__ int cur[TILE];
    const int bg = blockIdx.x;
    const int tid = threadIdx.x;
    const int base = bg * BCAP;
    const int cnt = gcursor[bg] - base;
    if (tid < TILE) { hist[tid] = 0; cur[tid] = 0; }
    __syncthreads();
    for (int i = tid; i < cnt; i += 256) {
        unsigned v = bucketed[base + i];
        pk[i] = v;
        atomicAdd(&hist[(v >> 16) & 63u], 1);
    }
    __syncthreads();
    if (tid < 64) {                      // wave 0: exclusive scan of 64 bins
        int v = hist[tid];
        int inc = v;
        #pragma unroll
        for (int off = 1; off < 64; off <<= 1) {
            int n = __shfl_up(inc, off, 64);
            if (tid >= off) inc += n;
        }
        scn[tid] = inc - v;
    }
    __syncthreads();
    for (int i = tid; i < cnt; i += 256) {
        unsigned v = pk[i];
        int dl = (int)((v >> 16) & 63u);
        int pos = scn[dl] + atomicAdd(&cur[dl], 1);
        srt[pos] = v & 0xFFFFu;          // keep src only
    }
    __syncthreads();
    for (int i = tid; i < cnt; i += 256) bucketed[base + i] = srt[i];
    if (tid < 64) {
        int t = bg / NBPT;
        int node = (bg - t * NBPT) * TILE + tid;
        if (node < NN) {
            int g = t * NN + node;
            begA[g] = base + scn[tid];
            endA[g] = base + scn[tid] + hist[tid];
        }
    }
}

// ---------------- fused score+softmax+aggregate+ELU, one wave per (type,dst) ----------------
__global__ __launch_bounds__(256) void gat_fused_kernel(
    const int* __restrict__ begA, const int* __restrict__ endA,
    const unsigned* __restrict__ ssrc,
    const float* __restrict__ es, const float* __restrict__ ed,
    const __half* __restrict__ h16,
    float* __restrict__ out)
{
    const int g = blockIdx.x * 4 + (threadIdx.x >> 6);
    if (g >= NT * NN) return;
    const int lane = threadIdx.x & 63;
    const int t = g / NN;
    const int dst = g - t * NN;
    const int beg = begA[g], end = endA[g];
    const int hd = lane >> 4;                         // head of dims (2l, 2l+1)
    const float* es_t = es + (size_t)t * NN * NH;
    const float edv = ed[(size_t)g * NH + (lane & 3)];
    const __half2* h2 = reinterpret_cast<const __half2*>(h16 + (size_t)t * NN * IND);

    float acc0 = 0.f, acc1 = 0.f, dsum = 0.f;

    for (int base = beg; base < end; base += 16) {
        int ne = end - base; if (ne > 16) ne = 16;
        const int ei = lane >> 2;
        float wv = 0.f; int sv = 0;
        if (ei < ne) {
            sv = (int)ssrc[base + ei];
            float s = es_t[(sv << 2) + (lane & 3)] + edv;
            s = s > 0.f ? s : NSLOPE * s;
            wv = __expf(s);
            dsum += wv;
        }
        for (int k = 0; k < ne; k++) {
            int   s = __shfl(sv, k << 2, 64);
            float w = __shfl(wv, (k << 2) | hd, 64);
            float2 hf = __half22float2(h2[(size_t)s * 64 + lane]);
            acc0 = fmaf(w, hf.x, acc0);
            acc1 = fmaf(w, hf.y, acc1);
        }
    }

    #pragma unroll
    for (int m = 4; m <= 32; m <<= 1) dsum += __shfl_xor(dsum, m, 64);
    float dn = __shfl(dsum, hd, 64) + 1e-9f;
    float v0 = acc0 / dn, v1 = acc1 / dn;
    float r0 = v0 > 0.f ? v0 : expm1f(v0);
    float r1 = v1 > 0.f ? v1 : expm1f(v1);

    float2* oa = reinterpret_cast<float2*>(out + (size_t)t * NN * IND + (size_t)dst * IND);
    float2* ob = reinterpret_cast<float2*>(out + (size_t)(NT + t) * NN * IND + (size_t)dst * IND);
    oa[lane] = make_float2(r0, r1);
    ob[lane] = make_float2(r0, r1);
}

extern "C" void kernel_launch(void* const* d_in, const int* in_sizes, int n_in,
                              void* d_out, int out_size, void* d_ws, size_t ws_size,
                              hipStream_t stream)
{
    const float* x     = (const float*)d_in[0];
    const int*   edges = (const int*)d_in[1];
    const float* W     = (const float*)d_in[2];
    const float* asrc  = (const float*)d_in[3];
    const float* adst  = (const float*)d_in[4];
    float* out = (float*)d_out;

    char* p = (char*)d_ws;
    __half*   h16      = (__half*)p;   p += (size_t)NT * NN * IND * 2;            // 38.4 MB
    float*    es       = (float*)p;    p += (size_t)NT * NN * NH * 4;             // 2.4 MB
    float*    ed       = (float*)p;    p += (size_t)NT * NN * NH * 4;             // 2.4 MB
    int*      gcursor  = (int*)p;      p += (size_t)NBTOT * 4;
    int*      begA     = (int*)p;      p += (size_t)NT * NN * 4;                  // 0.6 MB
    int*      endA     = (int*)p;      p += (size_t)NT * NN * 4;                  // 0.6 MB
    unsigned* bucketed = (unsigned*)p; p += ((size_t)NBTOT * BCAP + 1024) * 4;    // 12 MB

    init_gcursor_kernel<<<(NBTOT + 255) / 256, 256, 0, stream>>>(gcursor);
    bucket_scatter_kernel<<<(NT * NE + 16383) / 16384, 512, 0, stream>>>(edges, gcursor, bucketed);
    bucket_sort_kernel<<<NBTOT, 256, 0, stream>>>(bucketed, gcursor, begA, endA);

    for (int t = 0; t < NT; t++) {
        gemm_esrc_kernel<<<(NN + 31) / 32, 256, 0, stream>>>(
            x, W + (size_t)t * IND * IND,
            asrc + (size_t)t * NH * 32, adst + (size_t)t * NH * 32,
            h16 + (size_t)t * NN * IND,
            es + (size_t)t * NN * NH, ed + (size_t)t * NN * NH);
    }

    gat_fused_kernel<<<(NT * NN + 3) / 4, 256, 0, stream>>>(
        begA, endA, bucketed, es, ed, h16, out);
}

// Round 7
// 247.475 us; speedup vs baseline: 7.9741x; 1.6952x over previous
//
#include <hip/hip_runtime.h>
#include <hip/hip_fp16.h>
#include <math.h>

#define NN 50000
#define IND 128
#define NH 4
#define NE 800000
#define NT 3
#define NSLOPE 0.2f

#define TILE 64                    // dsts per bucket
#define NBPT 782                   // ceil(NN/TILE)
#define NBTOT (NT * NBPT)          // 2346
#define BCAP 1280                  // slots per bucket (Poisson λ=1024, +8σ)

typedef _Float16 f16x8 __attribute__((ext_vector_type(8)));
typedef _Float16 f16x4 __attribute__((ext_vector_type(4)));
typedef float    f32x4 __attribute__((ext_vector_type(4)));

// ---------------- W^T fp16 prep (one-time, tiny) ----------------
__global__ __launch_bounds__(256) void wt_prep_kernel(
    const float* __restrict__ W, __half* __restrict__ wt16g)
{
    int idx = blockIdx.x * 256 + threadIdx.x;
    if (idx >= NT * IND * IND) return;
    int t = idx / (IND * IND), r = idx - t * (IND * IND);
    int k = r >> 7, c = r & 127;
    wt16g[((size_t)t * IND + c) * IND + k] = (__half)W[idx];   // wt16g[t][c][k]
}

// ---------------- MFMA GEMM: h16 = x @ W_t (f16), fused es/ed ----------------
// Block 256 = 4 waves; wave -> 16 rows x 128 cols; grid (782, 3).
// A: row=l&15, k=(l>>4)*8+j (f32->f16 inline); B^T: col=l&15, same k (16B loads
// from wt16g); D: col=ct*16+(l&15), row=(l>>4)*4+r.  (m91/m92-verified layout)
__global__ __launch_bounds__(256) void gemm_mfma_kernel(
    const float* __restrict__ x, const __half* __restrict__ wt16g,
    const float* __restrict__ asrc, const float* __restrict__ adst,
    __half* __restrict__ h16, float* __restrict__ es, float* __restrict__ ed)
{
    __shared__ __align__(16) __half tile[4][16 * 136];   // pad 136 halves (272B = 17*16B)
    const int t = blockIdx.y;
    const int tid = threadIdx.x;
    const int wid = tid >> 6, lane = tid & 63;
    const int l15 = lane & 15, l4 = lane >> 4;
    const int r0 = blockIdx.x * 64 + wid * 16;
    const bool active = (r0 < NN);

    const __half* wt = wt16g + (size_t)t * IND * IND;
    const float* xrow = x + (size_t)((active ? r0 : 0) + l15) * IND;

    f32x4 acc[8];
    #pragma unroll
    for (int i = 0; i < 8; i++) acc[i] = (f32x4){0.f, 0.f, 0.f, 0.f};

    #pragma unroll
    for (int ks = 0; ks < 4; ks++) {
        const int kb = ks * 32 + l4 * 8;
        float4 x0 = *reinterpret_cast<const float4*>(xrow + kb);
        float4 x1 = *reinterpret_cast<const float4*>(xrow + kb + 4);
        f16x8 af;
        af[0] = (_Float16)x0.x; af[1] = (_Float16)x0.y;
        af[2] = (_Float16)x0.z; af[3] = (_Float16)x0.w;
        af[4] = (_Float16)x1.x; af[5] = (_Float16)x1.y;
        af[6] = (_Float16)x1.z; af[7] = (_Float16)x1.w;
        #pragma unroll
        for (int ct = 0; ct < 8; ct++) {
            f16x8 bf = *reinterpret_cast<const f16x8*>(wt + (size_t)(ct * 16 + l15) * IND + kb);
            acc[ct] = __builtin_amdgcn_mfma_f32_16x16x32_f16(af, bf, acc[ct], 0, 0, 0);
        }
    }

    // D -> LDS tile (row-major f16, padded)
    __half* tl = tile[wid];
    #pragma unroll
    for (int ct = 0; ct < 8; ct++)
        #pragma unroll
        for (int r = 0; r < 4; r++)
            tl[(l4 * 4 + r) * 136 + ct * 16 + l15] = (__half)acc[ct][r];
    __syncthreads();

    if (active) {
        // coalesced flush: 256 x 16B chunks per wave tile (16 rows x 128 halves)
        #pragma unroll
        for (int i = 0; i < 4; i++) {
            int c = lane + 64 * i;
            int row = c >> 4, off = (c & 15) * 8;
            f16x8 v = *reinterpret_cast<const f16x8*>(tl + row * 136 + off);
            *reinterpret_cast<f16x8*>(h16 + ((size_t)t * NN + r0 + row) * IND + off) = v;
        }
        // es/ed: lane = row16*4 + head
        int row16 = lane >> 2, head = lane & 3;
        const __half* hr = tl + row16 * 136 + head * 32;
        const float* av = asrc + ((size_t)t * NH + head) * 32;
        const float* bv = adst + ((size_t)t * NH + head) * 32;
        float se = 0.f, de = 0.f;
        #pragma unroll
        for (int jj = 0; jj < 4; jj++) {
            f16x8 hv = *reinterpret_cast<const f16x8*>(hr + jj * 8);
            #pragma unroll
            for (int j = 0; j < 8; j++) {
                float hf = (float)hv[j];
                se = fmaf(hf, av[jj * 8 + j], se);
                de = fmaf(hf, bv[jj * 8 + j], de);
            }
        }
        int n = r0 + row16;
        es[((size_t)t * NN + n) * NH + head] = se;
        ed[((size_t)t * NN + n) * NH + head] = de;
    }
}

// ---------------- bucket init + scatter ----------------
__global__ __launch_bounds__(256) void init_gcursor_kernel(int* __restrict__ gcursor)
{
    int i = blockIdx.x * 256 + threadIdx.x;
    if (i < NBTOT) gcursor[i] = i * BCAP;
}

// 8192 edges per WG: LDS hist -> global reservation -> packed coalesced-run writes
__global__ __launch_bounds__(512) void bucket_scatter_kernel(
    const int* __restrict__ edges, int* __restrict__ gcursor, unsigned* __restrict__ bucketed)
{
    __shared__ int cnt[NBTOT];
    __shared__ int base[NBTOT];
    const int tid = threadIdx.x;
    for (int i = tid; i < NBTOT; i += 512) cnt[i] = 0;
    __syncthreads();
    const long long gtot = (long long)NT * NE;
    const long long g0 = (long long)blockIdx.x * 8192;
    long long g1 = g0 + 8192; if (g1 > gtot) g1 = gtot;
    for (long long g = g0 + tid; g < g1; g += 512) {
        int t = (g >= 2LL * NE) ? 2 : (g >= NE ? 1 : 0);
        int e = (int)(g - (long long)t * NE);
        int d = edges[(size_t)t * 2 * NE + NE + e];
        atomicAdd(&cnt[t * NBPT + (d >> 6)], 1);
    }
    __syncthreads();
    for (int i = tid; i < NBTOT; i += 512) {
        int c = cnt[i];
        base[i] = c ? atomicAdd(&gcursor[i], c) : 0;
        cnt[i] = 0;
    }
    __syncthreads();
    for (long long g = g0 + tid; g < g1; g += 512) {
        int t = (g >= 2LL * NE) ? 2 : (g >= NE ? 1 : 0);
        int e = (int)(g - (long long)t * NE);
        const int* eb = edges + (size_t)t * 2 * NE;
        int s = eb[e], d = eb[NE + e];
        int bg = t * NBPT + (d >> 6);
        int pos = base[bg] + atomicAdd(&cnt[bg], 1);
        bucketed[pos] = (unsigned)s | ((unsigned)(d & 63) << 16);
    }
}

// ---------------- per-bucket in-LDS counting sort -> exact per-dst CSR ----------------
__global__ __launch_bounds__(512) void bucket_sort_kernel(
    unsigned* __restrict__ bucketed, const int* __restrict__ gcursor,
    int* __restrict__ begA, int* __restrict__ endA)
{
    __shared__ unsigned pk[BCAP];
    __shared__ unsigned srt[BCAP];
    __shared__ int hist[TILE];
    __shared__ int scn[TILE];
    __shared__ int cur[TILE];
    const int bg = blockIdx.x;
    const int tid = threadIdx.x;
    const int base = bg * BCAP;
    const int cnt = gcursor[bg] - base;
    if (tid < TILE) { hist[tid] = 0; cur[tid] = 0; }
    __syncthreads();
    for (int i = tid; i < cnt; i += 512) {
        unsigned v = bucketed[base + i];
        pk[i] = v;
        atomicAdd(&hist[(v >> 16) & 63u], 1);
    }
    __syncthreads();
    if (tid < 64) {
        int v = hist[tid];
        int inc = v;
        #pragma unroll
        for (int off = 1; off < 64; off <<= 1) {
            int n = __shfl_up(inc, off, 64);
            if (tid >= off) inc += n;
        }
        scn[tid] = inc - v;
    }
    __syncthreads();
    for (int i = tid; i < cnt; i += 512) {
        unsigned v = pk[i];
        int dl = (int)((v >> 16) & 63u);
        int pos = scn[dl] + atomicAdd(&cur[dl], 1);
        srt[pos] = v & 0xFFFFu;
    }
    __syncthreads();
    for (int i = tid; i < cnt; i += 512) bucketed[base + i] = srt[i];
    if (tid < 64) {
        int t = bg / NBPT;
        int node = (bg - t * NBPT) * TILE + tid;
        if (node < NN) {
            int g = t * NN + node;
            begA[g] = base + scn[tid];
            endA[g] = base + scn[tid] + hist[tid];
        }
    }
}

// ---------------- fused score+softmax+aggregate+ELU, one wave per (type,dst) ----------------
// Wave halves process 2 edges/step; lane covers 4 dims via half4 (8B) loads.
__global__ __launch_bounds__(256) void gat_fused_kernel(
    const int* __restrict__ begA, const int* __restrict__ endA,
    const unsigned* __restrict__ ssrc,
    const float* __restrict__ es, const float* __restrict__ ed,
    const __half* __restrict__ h16,
    float* __restrict__ out)
{
    const int g = blockIdx.x * 4 + (threadIdx.x >> 6);
    if (g >= NT * NN) return;
    const int lane = threadIdx.x & 63;
    const int t = g / NN;
    const int dst = g - t * NN;
    const int beg = begA[g], end = endA[g];
    const int el = lane >> 5, dl = lane & 31;      // half-select, dim-group (dims 4dl..4dl+3)
    const int hsel = dl >> 3;                      // head of this lane's dims
    const float* es_t = es + (size_t)t * NN * NH;
    const float edv = ed[(size_t)g * NH + (lane & 3)];
    const __half* h16_t = h16 + (size_t)t * NN * IND;

    float a0 = 0.f, a1 = 0.f, a2 = 0.f, a3 = 0.f, dsum = 0.f;

    for (int base = beg; base < end; base += 16) {
        int ne = end - base; if (ne > 16) ne = 16;
        const int ei = lane >> 2;
        float wv = 0.f; int sv = 0;
        if (ei < ne) {
            sv = (int)ssrc[base + ei];
            float s = es_t[(sv << 2) + (lane & 3)] + edv;
            s = s > 0.f ? s : NSLOPE * s;
            wv = __expf(s);
            dsum += wv;
        }
        int kk = 0;
        for (; kk + 2 <= ne; kk += 2) {
            int k2 = kk + el;
            int   sb = __shfl(sv, k2 << 2, 64);
            float wb = __shfl(wv, (k2 << 2) | hsel, 64);
            f16x4 hv = *reinterpret_cast<const f16x4*>(h16_t + ((size_t)sb << 7) + (dl << 2));
            a0 = fmaf(wb, (float)hv[0], a0);
            a1 = fmaf(wb, (float)hv[1], a1);
            a2 = fmaf(wb, (float)hv[2], a2);
            a3 = fmaf(wb, (float)hv[3], a3);
        }
        if (kk < ne) {                              // odd tail: el==0 half only
            int   sb = __shfl(sv, kk << 2, 64);
            float wb = __shfl(wv, (kk << 2) | hsel, 64);
            if (el == 0) {
                f16x4 hv = *reinterpret_cast<const f16x4*>(h16_t + ((size_t)sb << 7) + (dl << 2));
                a0 = fmaf(wb, (float)hv[0], a0);
                a1 = fmaf(wb, (float)hv[1], a1);
                a2 = fmaf(wb, (float)hv[2], a2);
                a3 = fmaf(wb, (float)hv[3], a3);
            }
        }
    }

    #pragma unroll
    for (int m = 4; m <= 32; m <<= 1) dsum += __shfl_xor(dsum, m, 64);
    a0 += __shfl_xor(a0, 32, 64);
    a1 += __shfl_xor(a1, 32, 64);
    a2 += __shfl_xor(a2, 32, 64);
    a3 += __shfl_xor(a3, 32, 64);
    float dn = __shfl(dsum, hsel, 64) + 1e-9f;

    if (el == 0) {
        float v0 = a0 / dn, v1 = a1 / dn, v2 = a2 / dn, v3 = a3 / dn;
        f32x4 o;
        o[0] = v0 > 0.f ? v0 : expm1f(v0);
        o[1] = v1 > 0.f ? v1 : expm1f(v1);
        o[2] = v2 > 0.f ? v2 : expm1f(v2);
        o[3] = v3 > 0.f ? v3 : expm1f(v3);
        float* obase = out + (size_t)t * NN * IND + ((size_t)dst << 7) + (dl << 2);
        __builtin_nontemporal_store(o, reinterpret_cast<f32x4*>(obase));
        __builtin_nontemporal_store(o, reinterpret_cast<f32x4*>(obase + (size_t)NT * NN * IND));
    }
}

extern "C" void kernel_launch(void* const* d_in, const int* in_sizes, int n_in,
                              void* d_out, int out_size, void* d_ws, size_t ws_size,
                              hipStream_t stream)
{
    const float* x     = (const float*)d_in[0];
    const int*   edges = (const int*)d_in[1];
    const float* W     = (const float*)d_in[2];
    const float* asrc  = (const float*)d_in[3];
    const float* adst  = (const float*)d_in[4];
    float* out = (float*)d_out;

    char* p = (char*)d_ws;
    __half*   h16      = (__half*)p;   p += (size_t)NT * NN * IND * 2;            // 38.4 MB
    float*    es       = (float*)p;    p += (size_t)NT * NN * NH * 4;             // 2.4 MB
    float*    ed       = (float*)p;    p += (size_t)NT * NN * NH * 4;             // 2.4 MB
    int*      gcursor  = (int*)p;      p += (size_t)NBTOT * 4;
    int*      begA     = (int*)p;      p += (size_t)NT * NN * 4;
    int*      endA     = (int*)p;      p += (size_t)NT * NN * 4;
    __half*   wt16g    = (__half*)p;   p += (size_t)NT * IND * IND * 2;           // 96 KB
    unsigned* bucketed = (unsigned*)p; p += ((size_t)NBTOT * BCAP + 1024) * 4;    // 12 MB

    wt_prep_kernel<<<(NT * IND * IND + 255) / 256, 256, 0, stream>>>(W, wt16g);
    init_gcursor_kernel<<<(NBTOT + 255) / 256, 256, 0, stream>>>(gcursor);
    bucket_scatter_kernel<<<(NT * NE + 8191) / 8192, 512, 0, stream>>>(edges, gcursor, bucketed);
    bucket_sort_kernel<<<NBTOT, 512, 0, stream>>>(bucketed, gcursor, begA, endA);

    dim3 ggrid((NN + 63) / 64, NT);
    gemm_mfma_kernel<<<ggrid, 256, 0, stream>>>(x, wt16g, asrc, adst, h16, es, ed);

    gat_fused_kernel<<<(NT * NN + 3) / 4, 256, 0, stream>>>(
        begA, endA, bucketed, es, ed, h16, out);
}

// Round 8
// 226.487 us; speedup vs baseline: 8.7130x; 1.0927x over previous
//
#include <hip/hip_runtime.h>
#include <hip/hip_fp16.h>
#include <math.h>

#define NN 50000
#define IND 128
#define NH 4
#define NE 800000
#define NT 3
#define NSLOPE 0.2f

#define TILE 64                    // dsts per bucket
#define NBPT 782                   // ceil(NN/TILE)
#define NBTOT (NT * NBPT)          // 2346
#define BCAP 1280                  // slots per bucket (Poisson λ=1024, +8σ)

#define SCB ((NT * NE + 8191) / 8192)   // 293 scatter blocks
#define GXB ((NN + 127) / 128)          // 391 gemm blocks per type

typedef _Float16 f16x8 __attribute__((ext_vector_type(8)));
typedef float    f32x4 __attribute__((ext_vector_type(4)));

// ---------------- prep: W^T fp16 + gcursor init ----------------
__global__ __launch_bounds__(256) void prep_kernel(
    const float* __restrict__ W, __half* __restrict__ wt16g, int* __restrict__ gcursor)
{
    int idx = blockIdx.x * 256 + threadIdx.x;
    if (idx < NT * IND * IND) {
        int t = idx / (IND * IND), r = idx - t * (IND * IND);
        int k = r >> 7, c = r & 127;
        wt16g[((size_t)t * IND + c) * IND + k] = (__half)W[idx];   // wt16g[t][c][k]
    }
    if (idx < NBTOT) gcursor[idx] = idx * BCAP;
}

// ---------------- combined: bucket_scatter (blocks 0..SCB-1) + MFMA GEMM ----------------
// GEMM: 8 waves x 16 rows = 128 rows/block; A row=l&15, k=(l>>4)*8+j; B^T col=l&15;
// D col=ct*16+(l&15), row=(l>>4)*4+r (m91/m92-verified layout).
__global__ __launch_bounds__(512) void scatter_gemm_kernel(
    const int* __restrict__ edges, int* __restrict__ gcursor, unsigned* __restrict__ bucketed,
    const float* __restrict__ x, const __half* __restrict__ wt16g,
    const float* __restrict__ asrc, const float* __restrict__ adst,
    __half* __restrict__ h16, float* __restrict__ es, float* __restrict__ ed)
{
    __shared__ __align__(16) char ldsbuf[34816];
    const int tid = threadIdx.x;

    if (blockIdx.x < SCB) {
        // ---- bucket scatter: 8192 edges/block ----
        int* cnt = (int*)ldsbuf;
        int* bas = cnt + NBTOT;
        for (int i = tid; i < NBTOT; i += 512) cnt[i] = 0;
        __syncthreads();
        const long long gtot = (long long)NT * NE;
        const long long g0 = (long long)blockIdx.x * 8192;
        long long g1 = g0 + 8192; if (g1 > gtot) g1 = gtot;
        for (long long g = g0 + tid; g < g1; g += 512) {
            int t = (g >= 2LL * NE) ? 2 : (g >= NE ? 1 : 0);
            int e = (int)(g - (long long)t * NE);
            int d = edges[(size_t)t * 2 * NE + NE + e];
            atomicAdd(&cnt[t * NBPT + (d >> 6)], 1);
        }
        __syncthreads();
        for (int i = tid; i < NBTOT; i += 512) {
            int c = cnt[i];
            bas[i] = c ? atomicAdd(&gcursor[i], c) : 0;
            cnt[i] = 0;
        }
        __syncthreads();
        for (long long g = g0 + tid; g < g1; g += 512) {
            int t = (g >= 2LL * NE) ? 2 : (g >= NE ? 1 : 0);
            int e = (int)(g - (long long)t * NE);
            const int* eb = edges + (size_t)t * 2 * NE;
            int s = eb[e], d = eb[NE + e];
            int bg = t * NBPT + (d >> 6);
            int pos = bas[bg] + atomicAdd(&cnt[bg], 1);
            bucketed[pos] = (unsigned)s | ((unsigned)(d & 63) << 16);
        }
        return;
    }

    // ---- MFMA GEMM ----
    const int bx = blockIdx.x - SCB;
    const int t  = bx / GXB;
    const int gx = bx - t * GXB;
    __half* tile = (__half*)ldsbuf;
    const int wid = tid >> 6, lane = tid & 63;
    __half* tl = tile + wid * (16 * 136);
    const int l15 = lane & 15, l4 = lane >> 4;
    const int r0 = gx * 128 + wid * 16;
    const bool active = (r0 < NN);           // NN%16==0 -> whole wave active or not

    const __half* wt = wt16g + (size_t)t * IND * IND;
    const float* xrow = x + (size_t)((active ? r0 : 0) + l15) * IND;

    f32x4 acc[8];
    #pragma unroll
    for (int i = 0; i < 8; i++) acc[i] = (f32x4){0.f, 0.f, 0.f, 0.f};

    #pragma unroll
    for (int ks = 0; ks < 4; ks++) {
        const int kb = ks * 32 + l4 * 8;
        float4 x0 = *reinterpret_cast<const float4*>(xrow + kb);
        float4 x1 = *reinterpret_cast<const float4*>(xrow + kb + 4);
        f16x8 af;
        af[0] = (_Float16)x0.x; af[1] = (_Float16)x0.y;
        af[2] = (_Float16)x0.z; af[3] = (_Float16)x0.w;
        af[4] = (_Float16)x1.x; af[5] = (_Float16)x1.y;
        af[6] = (_Float16)x1.z; af[7] = (_Float16)x1.w;
        #pragma unroll
        for (int ct = 0; ct < 8; ct++) {
            f16x8 bf = *reinterpret_cast<const f16x8*>(wt + (size_t)(ct * 16 + l15) * IND + kb);
            acc[ct] = __builtin_amdgcn_mfma_f32_16x16x32_f16(af, bf, acc[ct], 0, 0, 0);
        }
    }

    #pragma unroll
    for (int ct = 0; ct < 8; ct++)
        #pragma unroll
        for (int r = 0; r < 4; r++)
            tl[(l4 * 4 + r) * 136 + ct * 16 + l15] = (__half)acc[ct][r];
    __syncthreads();

    if (active) {
        #pragma unroll
        for (int i = 0; i < 4; i++) {        // 256 x 16B chunks: full 16x128 tile
            int c = lane + 64 * i;
            int row = c >> 4, off = (c & 15) * 8;
            f16x8 v = *reinterpret_cast<const f16x8*>(tl + row * 136 + off);
            *reinterpret_cast<f16x8*>(h16 + ((size_t)t * NN + r0 + row) * IND + off) = v;
        }
        int row16 = lane >> 2, head = lane & 3;
        const __half* hr = tl + row16 * 136 + head * 32;
        const float* av = asrc + ((size_t)t * NH + head) * 32;
        const float* bv = adst + ((size_t)t * NH + head) * 32;
        float se = 0.f, de = 0.f;
        #pragma unroll
        for (int jj = 0; jj < 4; jj++) {
            f16x8 hv = *reinterpret_cast<const f16x8*>(hr + jj * 8);
            #pragma unroll
            for (int j = 0; j < 8; j++) {
                float hf = (float)hv[j];
                se = fmaf(hf, av[jj * 8 + j], se);
                de = fmaf(hf, bv[jj * 8 + j], de);
            }
        }
        int n = r0 + row16;
        es[((size_t)t * NN + n) * NH + head] = se;
        ed[((size_t)t * NN + n) * NH + head] = de;
    }
}

// ---------------- per-bucket: LDS sort -> fused score+softmax+aggregate+ELU ----------------
// 512 thr = 8 waves; sort ~1024 edges into per-dst runs in LDS, then wave w
// processes dsts w*8..w*8+7. Inner loop: v_fma_mix_f32 (f16 h, f32 w/acc).
__global__ __launch_bounds__(512) void gat_bucket_kernel(
    const unsigned* __restrict__ bucketed, const int* __restrict__ gcursor,
    const float* __restrict__ es, const float* __restrict__ ed,
    const __half* __restrict__ h16, float* __restrict__ out)
{
    __shared__ unsigned pk[BCAP];
    __shared__ unsigned srt[BCAP];
    __shared__ int hist[TILE], scn[TILE], cur[TILE];
    const int bg = blockIdx.x;
    const int t = bg / NBPT;
    const int node0 = (bg - t * NBPT) * TILE;
    const int tid = threadIdx.x;
    const int base = bg * BCAP;
    const int cnt = gcursor[bg] - base;

    if (tid < TILE) { hist[tid] = 0; cur[tid] = 0; }
    __syncthreads();
    for (int i = tid; i < cnt; i += 512) {
        unsigned v = bucketed[base + i];
        pk[i] = v;
        atomicAdd(&hist[(v >> 16) & 63u], 1);
    }
    __syncthreads();
    if (tid < 64) {
        int v = hist[tid];
        int inc = v;
        #pragma unroll
        for (int off = 1; off < 64; off <<= 1) {
            int n = __shfl_up(inc, off, 64);
            if (tid >= off) inc += n;
        }
        scn[tid] = inc - v;
    }
    __syncthreads();
    for (int i = tid; i < cnt; i += 512) {
        unsigned v = pk[i];
        int dl = (int)((v >> 16) & 63u);
        int pos = scn[dl] + atomicAdd(&cur[dl], 1);
        srt[pos] = v & 0xFFFFu;
    }
    __syncthreads();

    const int wid = tid >> 6, lane = tid & 63;
    const int el = lane >> 5, dl2 = lane & 31;   // half-select; dims 4*dl2..4*dl2+3
    const int hsel = dl2 >> 3;                   // head of this lane's dims
    const float* es_t = es + (size_t)t * NN * NH;
    const __half* h16_t = h16 + (size_t)t * NN * IND;

    for (int j = 0; j < 8; j++) {
        const int dloc = wid * 8 + j;
        const int node = node0 + dloc;
        if (node >= NN) break;
        const int beg = scn[dloc], nE = hist[dloc];
        const float edv = ed[((size_t)t * NN + node) * NH + (lane & 3)];

        float a0 = 0.f, a1 = 0.f, a2 = 0.f, a3 = 0.f, dsum = 0.f;

        for (int b2 = 0; b2 < nE; b2 += 16) {
            int ne = nE - b2; if (ne > 16) ne = 16;
            const int ei = lane >> 2;
            float wv = 0.f; int sv = 0;
            if (ei < ne) {
                sv = (int)srt[beg + b2 + ei];
                float s = es_t[(sv << 2) + (lane & 3)] + edv;
                s = s > 0.f ? s : NSLOPE * s;
                wv = __expf(s);
                dsum += wv;
            }
            int kk = 0;
            for (; kk + 2 <= ne; kk += 2) {
                int k2 = kk + el;
                int   sb = __shfl(sv, k2 << 2, 64);
                float wb = __shfl(wv, (k2 << 2) | hsel, 64);
                uint2 hv = *reinterpret_cast<const uint2*>(h16_t + ((size_t)sb << 7) + (dl2 << 2));
                asm("v_fma_mix_f32 %0, %1, %2, %0 op_sel:[0,0,0] op_sel_hi:[1,0,0]" : "+v"(a0) : "v"(hv.x), "v"(wb));
                asm("v_fma_mix_f32 %0, %1, %2, %0 op_sel:[1,0,0] op_sel_hi:[1,0,0]" : "+v"(a1) : "v"(hv.x), "v"(wb));
                asm("v_fma_mix_f32 %0, %1, %2, %0 op_sel:[0,0,0] op_sel_hi:[1,0,0]" : "+v"(a2) : "v"(hv.y), "v"(wb));
                asm("v_fma_mix_f32 %0, %1, %2, %0 op_sel:[1,0,0] op_sel_hi:[1,0,0]" : "+v"(a3) : "v"(hv.y), "v"(wb));
            }
            if (kk < ne) {                       // odd tail: el==0 half only
                int   sb = __shfl(sv, kk << 2, 64);
                float wb = __shfl(wv, (kk << 2) | hsel, 64);
                if (el == 0) {
                    uint2 hv = *reinterpret_cast<const uint2*>(h16_t + ((size_t)sb << 7) + (dl2 << 2));
                    asm("v_fma_mix_f32 %0, %1, %2, %0 op_sel:[0,0,0] op_sel_hi:[1,0,0]" : "+v"(a0) : "v"(hv.x), "v"(wb));
                    asm("v_fma_mix_f32 %0, %1, %2, %0 op_sel:[1,0,0] op_sel_hi:[1,0,0]" : "+v"(a1) : "v"(hv.x), "v"(wb));
                    asm("v_fma_mix_f32 %0, %1, %2, %0 op_sel:[0,0,0] op_sel_hi:[1,0,0]" : "+v"(a2) : "v"(hv.y), "v"(wb));
                    asm("v_fma_mix_f32 %0, %1, %2, %0 op_sel:[1,0,0] op_sel_hi:[1,0,0]" : "+v"(a3) : "v"(hv.y), "v"(wb));
                }
            }
        }

        #pragma unroll
        for (int m = 4; m <= 32; m <<= 1) dsum += __shfl_xor(dsum, m, 64);
        a0 += __shfl_xor(a0, 32, 64);
        a1 += __shfl_xor(a1, 32, 64);
        a2 += __shfl_xor(a2, 32, 64);
        a3 += __shfl_xor(a3, 32, 64);
        float dn = __shfl(dsum, hsel, 64) + 1e-9f;

        if (el == 0) {
            float v0 = a0 / dn, v1 = a1 / dn, v2 = a2 / dn, v3 = a3 / dn;
            f32x4 o;
            o[0] = v0 > 0.f ? v0 : expm1f(v0);
            o[1] = v1 > 0.f ? v1 : expm1f(v1);
            o[2] = v2 > 0.f ? v2 : expm1f(v2);
            o[3] = v3 > 0.f ? v3 : expm1f(v3);
            float* obase = out + (size_t)t * NN * IND + ((size_t)node << 7) + (dl2 << 2);
            __builtin_nontemporal_store(o, reinterpret_cast<f32x4*>(obase));
            __builtin_nontemporal_store(o, reinterpret_cast<f32x4*>(obase + (size_t)NT * NN * IND));
        }
    }
}

extern "C" void kernel_launch(void* const* d_in, const int* in_sizes, int n_in,
                              void* d_out, int out_size, void* d_ws, size_t ws_size,
                              hipStream_t stream)
{
    const float* x     = (const float*)d_in[0];
    const int*   edges = (const int*)d_in[1];
    const float* W     = (const float*)d_in[2];
    const float* asrc  = (const float*)d_in[3];
    const float* adst  = (const float*)d_in[4];
    float* out = (float*)d_out;

    char* p = (char*)d_ws;
    __half*   h16      = (__half*)p;   p += (size_t)NT * NN * IND * 2;            // 38.4 MB
    float*    es       = (float*)p;    p += (size_t)NT * NN * NH * 4;             // 2.4 MB
    float*    ed       = (float*)p;    p += (size_t)NT * NN * NH * 4;             // 2.4 MB
    int*      gcursor  = (int*)p;      p += (size_t)NBTOT * 4;
    __half*   wt16g    = (__half*)p;   p += (size_t)NT * IND * IND * 2;           // 96 KB
    unsigned* bucketed = (unsigned*)p; p += ((size_t)NBTOT * BCAP + 1024) * 4;    // 12 MB

    prep_kernel<<<(NT * IND * IND + 255) / 256, 256, 0, stream>>>(W, wt16g, gcursor);
    scatter_gemm_kernel<<<SCB + NT * GXB, 512, 0, stream>>>(
        edges, gcursor, bucketed, x, wt16g, asrc, adst, h16, es, ed);
    gat_bucket_kernel<<<NBTOT, 512, 0, stream>>>(bucketed, gcursor, es, ed, h16, out);
}